// Round 24
// baseline (24.459 us; speedup 1.0000x reference)
//
#include <hip/hip_runtime.h>

#define IMG   512
#define NCLS  256
#define DIM   1024
#define HPW   32
#define TPB   16           // tokens per block = full MFMA M
#define NT    1024         // 16 waves; wave owns 64 dims
#define MAGIC 0x5EEDC0DEu

typedef short bf16x8 __attribute__((ext_vector_type(8)));
typedef float f32x4  __attribute__((ext_vector_type(4)));

__device__ inline ushort bf16rne(float v) {
    unsigned u = __float_as_uint(v);
    return (ushort)((u + 0x7fffu + ((u >> 16) & 1u)) >> 16);
}

// R23 skeleton (best: 18.75 us). Two changes:
//  (a) wave-split front: pack-load (waves 0-7) runs CONCURRENTLY with histogram
//      (waves 8-15); then copy-out concurrently with convert.
//  (b) non-temporal B loads (read-once data; keep L2 clean).
//   Tt2[dtile*4096 + ks*512 + g*128 + c*8 + j] = bf16(table[ks*32+g*8+j][dtile*16+c])
__global__ __launch_bounds__(NT)
void fused_one(const int* __restrict__ smap, const float* __restrict__ table,
               const float* __restrict__ gamma, const float* __restrict__ beta,
               float* __restrict__ out, ushort* __restrict__ Tt2,
               unsigned* __restrict__ flags)
{
    __shared__ unsigned cnt[TPB * NCLS];      // 16 KB
    __shared__ ushort   pk[2048];             // 4 KB pack staging
    __shared__ ushort   cntb[16][264];        // stride 528 B -> conflict-free b128
    __shared__ float    red[16][4][4][2];     // [wave][g][i][{s,s2}]

    const int t    = threadIdx.x;
    const int lane = t & 63;
    const int w    = t >> 6;
    const int c    = lane & 15;
    const int g    = lane >> 4;

    const int bid  = blockIdx.x;
    const int tok0 = bid * TPB;
    const int b    = tok0 >> 10;
    const int ph   = (tok0 >> 5) & 31;
    const int pw0  = tok0 & 31;               // 0 or 16

    const int dtile = bid >> 1;
    const int kh    = bid & 1;

    // ---- 1) zero hist (LDS-only, fast) ----
    #pragma unroll
    for (int i = t; i < TPB * NCLS; i += NT) cnt[i] = 0u;
    __syncthreads();

    // ---- 2) SPLIT: waves 0-7 pack-load+scatter  ||  waves 8-15 histogram ----
    if (t < 512) {
        const int cls  = kh * 128 + (t >> 2);
        const int quad = t & 3;
        const float4 v = *reinterpret_cast<const float4*>(
            table + (size_t)cls * DIM + dtile * 16 + quad * 4);
        const int ks = cls >> 5, gg = (cls >> 3) & 3, j = cls & 7;
        ushort* dst = pk + (ks & 3) * 512 + gg * 128 + j;
        dst[(quad * 4 + 0) * 8] = bf16rne(v.x);
        dst[(quad * 4 + 1) * 8] = bf16rne(v.y);
        dst[(quad * 4 + 2) * 8] = bf16rne(v.z);
        dst[(quad * 4 + 3) * 8] = bf16rne(v.w);
    } else {
        const int tt  = t - 512;
        const int row = tt >> 5;              // 0..15
        const int col = (tt & 31) * 8;        // 0..248 (8 px within one patch)
        const int* bp = smap + ((size_t)b * IMG + (size_t)(ph * 16 + row)) * IMG
                             + pw0 * 16 + col;
        const int4 q0 = *reinterpret_cast<const int4*>(bp);
        const int4 q1 = *reinterpret_cast<const int4*>(bp + 4);
        unsigned* hp = &cnt[(col >> 4) * NCLS];
        atomicAdd(&hp[min(max(q0.x, 0), NCLS - 1)], 1u);
        atomicAdd(&hp[min(max(q0.y, 0), NCLS - 1)], 1u);
        atomicAdd(&hp[min(max(q0.z, 0), NCLS - 1)], 1u);
        atomicAdd(&hp[min(max(q0.w, 0), NCLS - 1)], 1u);
        atomicAdd(&hp[min(max(q1.x, 0), NCLS - 1)], 1u);
        atomicAdd(&hp[min(max(q1.y, 0), NCLS - 1)], 1u);
        atomicAdd(&hp[min(max(q1.z, 0), NCLS - 1)], 1u);
        atomicAdd(&hp[min(max(q1.w, 0), NCLS - 1)], 1u);
    }
    __syncthreads();                          // pk + cnt complete

    // ---- 3) SPLIT: waves 0-7 copy-out (system scope)  ||  waves 8-15 convert ----
    if (t < 512) {
        #pragma unroll
        for (int k = 0; k < 2; ++k) {
            const int tt = t * 2 + k;         // 0..1023 dwords
            const unsigned val = (unsigned)pk[tt * 2] | ((unsigned)pk[tt * 2 + 1] << 16);
            __hip_atomic_store((unsigned*)Tt2 + (size_t)dtile * 2048 + kh * 1024 + tt, val,
                               __ATOMIC_RELAXED, __HIP_MEMORY_SCOPE_SYSTEM);
        }
    } else {
        #pragma unroll
        for (int i = t - 512; i < TPB * NCLS; i += 512)
            cntb[i >> 8][i & 255] =
                (ushort)(__float_as_uint((float)cnt[i] * (1.f / 256.f)) >> 16);
    }
    __syncthreads();                          // drains every wave's stores (vmcnt 0)

    // ---- 4) publish pack completion (system-scope release) ----
    if (t == 0)
        __hip_atomic_store(&flags[bid], MAGIC, __ATOMIC_RELEASE, __HIP_MEMORY_SCOPE_SYSTEM);

    // ---- 5) gate: RELAXED polls (no cache-inv storm), then ONE acquire ----
    if (t < 128) {
        while (__hip_atomic_load(&flags[t], __ATOMIC_RELAXED,
                                 __HIP_MEMORY_SCOPE_SYSTEM) != MAGIC) {}
    }
    __syncthreads();
    if (t == 0) {
        unsigned x = __hip_atomic_load(&flags[0], __ATOMIC_ACQUIRE,
                                       __HIP_MEMORY_SCOPE_SYSTEM);
        asm volatile("" :: "v"(x));           // keep the acquire load live
    }
    __syncthreads();

    // ---- 6) MFMA K-loop (R23 structure; nt B loads) ----
    f32x4 acc[4];
    #pragma unroll
    for (int i = 0; i < 4; ++i) acc[i] = (f32x4){0.f, 0.f, 0.f, 0.f};

    const ushort* bt = Tt2 + (size_t)(w * 4) * 4096 + (size_t)lane * 8;
    #pragma unroll 2
    for (int ks = 0; ks < 8; ++ks) {
        const bf16x8 a = *reinterpret_cast<const bf16x8*>(&cntb[c][ks * 32 + g * 8]);
        bf16x8 bfv[4];
        #pragma unroll
        for (int nf = 0; nf < 4; ++nf)
            bfv[nf] = __builtin_nontemporal_load(
                reinterpret_cast<const bf16x8*>(bt + (size_t)nf * 4096 + ks * 512));
        #pragma unroll
        for (int nf = 0; nf < 4; ++nf)
            acc[nf] = __builtin_amdgcn_mfma_f32_16x16x32_bf16(a, bfv[nf], acc[nf], 0, 0, 0);
    }

    // ---- 7) pos-embed + LN partials (verbatim R23) ----
    const int quad   = w >> 2;
    const int cosSel = quad & 1;
    float ls[4]  = {0, 0, 0, 0};
    float ls2[4] = {0, 0, 0, 0};

    #pragma unroll
    for (int nf = 0; nf < 4; ++nf) {
        const int dlow = (w & 3) * 64 + nf * 16 + c;
        const float omega = exp2f((float)dlow * (-13.287712379549449f / 256.f));
        if (quad < 2) {
            float sv, cv; __sincosf((float)ph * omega, &sv, &cv);
            const float v = cosSel ? cv : sv;
            #pragma unroll
            for (int i = 0; i < 4; ++i) acc[nf][i] += v;
        } else {
            #pragma unroll
            for (int i = 0; i < 4; ++i) {
                float sv, cv; __sincosf((float)(pw0 + g * 4 + i) * omega, &sv, &cv);
                acc[nf][i] += cosSel ? cv : sv;
            }
        }
        #pragma unroll
        for (int i = 0; i < 4; ++i) { ls[i] += acc[nf][i]; ls2[i] += acc[nf][i] * acc[nf][i]; }
    }

    #pragma unroll
    for (int off = 1; off < 16; off <<= 1) {
        #pragma unroll
        for (int i = 0; i < 4; ++i) {
            ls[i]  += __shfl_xor(ls[i],  off, 64);
            ls2[i] += __shfl_xor(ls2[i], off, 64);
        }
    }
    if (c == 0) {
        #pragma unroll
        for (int i = 0; i < 4; ++i) { red[w][g][i][0] = ls[i]; red[w][g][i][1] = ls2[i]; }
    }
    __syncthreads();

    // ---- 8) finalize LN + store (verbatim R23) ----
    {
        float mu[4], rs[4];
        #pragma unroll
        for (int i = 0; i < 4; ++i) {
            float S = 0.f, S2 = 0.f;
            #pragma unroll
            for (int ww = 0; ww < 16; ++ww) { S += red[ww][g][i][0]; S2 += red[ww][g][i][1]; }
            mu[i] = S * (1.f / DIM);
            rs[i] = rsqrtf(S2 * (1.f / DIM) - mu[i] * mu[i] + 1e-5f);
        }
        #pragma unroll
        for (int nf = 0; nf < 4; ++nf) {
            const int d = w * 64 + nf * 16 + c;
            const float gv = gamma[d], bv = beta[d];
            #pragma unroll
            for (int i = 0; i < 4; ++i) {
                const int r = g * 4 + i;
                out[(size_t)(tok0 + r) * DIM + d] = (acc[nf][i] - mu[i]) * rs[i] * gv + bv;
            }
        }
    }
}

extern "C" void kernel_launch(void* const* d_in, const int* in_sizes, int n_in,
                              void* d_out, int out_size, void* d_ws, size_t ws_size,
                              hipStream_t stream) {
    const int*   smap  = (const int*)d_in[0];
    const float* table = (const float*)d_in[1];
    const float* gamma = (const float*)d_in[2];
    const float* beta  = (const float*)d_in[3];
    float*       out   = (float*)d_out;

    const int batches = in_sizes[0] / (IMG * IMG);       // = 2
    const int tokens  = batches * HPW * HPW;             // 2048
    const int nblk    = tokens / TPB;                    // 128

    ushort*   Tt2   = (ushort*)d_ws;                     // 512 KB packed table
    unsigned* flags = (unsigned*)(Tt2 + (size_t)64 * 4096);

    fused_one<<<nblk, NT, 0, stream>>>(smap, table, gamma, beta, out, Tt2, flags);
}